// Round 4
// baseline (99.209 us; speedup 1.0000x reference)
//
#include <hip/hip_runtime.h>
#include <hip/hip_bf16.h>

typedef __bf16 bf16_t;
typedef __bf16 bf16x8 __attribute__((ext_vector_type(8)));
typedef float  f32x4  __attribute__((ext_vector_type(4)));

#define M_ROWS 12544   // 64*14*14
#define K_DIM  512
#define N_DIM  2048
#define BM 128
#define BN 128
#define BK 64

// ---------------- Kernel 1: residual add + LayerNorm -> bf16 ----------------
// One wave (64 lanes) per row of 512; 8 floats/lane; wave shuffle reduction.
__global__ __launch_bounds__(256) void add_ln_bf16(
    const float* __restrict__ xa, const float* __restrict__ xb,
    const float* __restrict__ gamma, const float* __restrict__ beta,
    bf16_t* __restrict__ xn)
{
    const int wave = threadIdx.x >> 6;
    const int lane = threadIdx.x & 63;
    const int row  = blockIdx.x * 4 + wave;
    const size_t base = (size_t)row * K_DIM + lane * 8;

    float4 a0 = *(const float4*)(xa + base);
    float4 a1 = *(const float4*)(xa + base + 4);
    float4 b0 = *(const float4*)(xb + base);
    float4 b1 = *(const float4*)(xb + base + 4);

    float v[8] = {a0.x + b0.x, a0.y + b0.y, a0.z + b0.z, a0.w + b0.w,
                  a1.x + b1.x, a1.y + b1.y, a1.z + b1.z, a1.w + b1.w};
    float s = 0.f, sq = 0.f;
#pragma unroll
    for (int j = 0; j < 8; ++j) { s += v[j]; sq += v[j] * v[j]; }
#pragma unroll
    for (int off = 32; off >= 1; off >>= 1) {
        s  += __shfl_xor(s, off, 64);
        sq += __shfl_xor(sq, off, 64);
    }
    const float mean = s * (1.0f / 512.0f);
    const float var  = sq * (1.0f / 512.0f) - mean * mean;
    const float rstd = rsqrtf(var + 1e-5f);

    float4 g0  = *(const float4*)(gamma + lane * 8);
    float4 g1  = *(const float4*)(gamma + lane * 8 + 4);
    float4 be0 = *(const float4*)(beta  + lane * 8);
    float4 be1 = *(const float4*)(beta  + lane * 8 + 4);
    float g[8]  = {g0.x, g0.y, g0.z, g0.w, g1.x, g1.y, g1.z, g1.w};
    float bt[8] = {be0.x, be0.y, be0.z, be0.w, be1.x, be1.y, be1.z, be1.w};

    bf16x8 o;
#pragma unroll
    for (int j = 0; j < 8; ++j)
        o[j] = (bf16_t)((v[j] - mean) * rstd * g[j] + bt[j]);
    *(bf16x8*)(xn + base) = o;
}

// ---------------- Kernel 2: W [512][2048] f32 -> Wt [2048][512] bf16 --------
__global__ __launch_bounds__(256) void wt_bf16(
    const float* __restrict__ W, bf16_t* __restrict__ Wt)
{
    __shared__ float t[32][33];
    const int bk = blockIdx.x & 15;   // 16 k-tiles of 32
    const int bn = blockIdx.x >> 4;   // 64 n-tiles of 32
    const int tx = threadIdx.x & 31;
    const int ty = threadIdx.x >> 5;  // 0..7
#pragma unroll
    for (int r = 0; r < 4; ++r) {
        int k = bk * 32 + ty + r * 8;
        t[ty + r * 8][tx] = W[(size_t)k * N_DIM + bn * 32 + tx];
    }
    __syncthreads();
#pragma unroll
    for (int r = 0; r < 4; ++r) {
        int n = bn * 32 + ty + r * 8;
        Wt[(size_t)n * K_DIM + bk * 32 + tx] = (bf16_t)t[tx][ty + r * 8];
    }
}

// ---------------- Kernel 3: bf16 MFMA GEMM + bias + exact GELU --------------
__device__ __forceinline__ void gload_lds16(const void* g, void* l) {
    // width=16 async global->LDS; LDS dest = wave-uniform base + lane*16
    __builtin_amdgcn_global_load_lds(
        (const __attribute__((address_space(1))) void*)g,
        (__attribute__((address_space(3))) void*)l, 16, 0, 0);
}

__global__ __launch_bounds__(256) void gemm_bias_gelu(
    const bf16_t* __restrict__ A,   // [M_ROWS][K_DIM] bf16 (normalized x)
    const bf16_t* __restrict__ Bt,  // [N_DIM][K_DIM]  bf16 (W^T)
    const float* __restrict__ bias, // [N_DIM]
    float* __restrict__ out)        // [M_ROWS][N_DIM] f32
{
    __shared__ bf16_t As[BM * BK];  // 16 KB, linear (required by global_load_lds)
    __shared__ bf16_t Bs[BN * BK];  // 16 KB

    const int tiles_m = M_ROWS / BM;       // 98
    const int tm = blockIdx.x % tiles_m;
    const int tn = blockIdx.x / tiles_m;

    const int tid  = threadIdx.x;
    const int wave = tid >> 6;             // 0..3
    const int lane = tid & 63;
    const int wr = wave >> 1;              // 2x2 wave grid, each wave 64x64 out
    const int wc = wave & 1;

    const bf16_t* Ab = A  + (size_t)tm * BM * K_DIM;
    const bf16_t* Bb = Bt + (size_t)tn * BN * K_DIM;

    const int srow = lane >> 3;            // 0..7 row within 8-row segment
    const int skk  = (lane & 7) * 8;       // 0..56, 8 bf16 = 16 B per lane

    f32x4 acc[4][4];
#pragma unroll
    for (int m = 0; m < 4; ++m)
#pragma unroll
        for (int n = 0; n < 4; ++n)
            acc[m][n] = (f32x4){0.f, 0.f, 0.f, 0.f};

    for (int k0 = 0; k0 < K_DIM; k0 += BK) {
        // Stage A and B tiles: each wave owns 4 segments (8 rows x 64 k each).
        // LDS linear order == lane order (lane*16B), source is per-lane.
#pragma unroll
        for (int c = 0; c < 4; ++c) {
            const int seg = wave * 4 + c;          // wave-uniform
            const int row = seg * 8 + srow;
            gload_lds16(Ab + (size_t)row * K_DIM + k0 + skk, As + seg * 512);
            gload_lds16(Bb + (size_t)row * K_DIM + k0 + skk, Bs + seg * 512);
        }
        __syncthreads();  // compiler emits vmcnt(0) drain before s_barrier

#pragma unroll
        for (int kk = 0; kk < 2; ++kk) {
            bf16x8 af[4], bfr[4];
#pragma unroll
            for (int m = 0; m < 4; ++m)
                af[m] = *(const bf16x8*)(As + (wr * 64 + m * 16 + (lane & 15)) * BK
                                            + kk * 32 + (lane >> 4) * 8);
#pragma unroll
            for (int n = 0; n < 4; ++n)
                bfr[n] = *(const bf16x8*)(Bs + (wc * 64 + n * 16 + (lane & 15)) * BK
                                             + kk * 32 + (lane >> 4) * 8);
#pragma unroll
            for (int m = 0; m < 4; ++m)
#pragma unroll
                for (int n = 0; n < 4; ++n)
                    acc[m][n] = __builtin_amdgcn_mfma_f32_16x16x32_bf16(
                        af[m], bfr[n], acc[m][n], 0, 0, 0);
        }
        __syncthreads();
    }

    // Epilogue: bias + exact GELU, scalar f32 stores.
    // C/D layout (m89/m91 verified): col = lane&15, row = (lane>>4)*4 + reg.
    const int rbase = tm * BM + wr * 64;
    const int cbase = tn * BN + wc * 64;
#pragma unroll
    for (int n = 0; n < 4; ++n) {
        const int col = cbase + n * 16 + (lane & 15);
        const float bv = bias[col];
#pragma unroll
        for (int m = 0; m < 4; ++m) {
#pragma unroll
            for (int i = 0; i < 4; ++i) {
                const int row = rbase + m * 16 + (lane >> 4) * 4 + i;
                const float x = acc[m][n][i] + bv;
                const float gl = 0.5f * x * (1.0f + erff(x * 0.70710678118654752f));
                out[(size_t)row * N_DIM + col] = gl;
            }
        }
    }
}

extern "C" void kernel_launch(void* const* d_in, const int* in_sizes, int n_in,
                              void* d_out, int out_size, void* d_ws, size_t ws_size,
                              hipStream_t stream)
{
    const float* x203  = (const float*)d_in[0];
    const float* x217  = (const float*)d_in[1];
    const float* gamma = (const float*)d_in[2];
    const float* beta  = (const float*)d_in[3];
    const float* W     = (const float*)d_in[4];
    const float* bias  = (const float*)d_in[5];
    float* out = (float*)d_out;

    // Workspace layout: xn bf16 [12544][512] (12.25 MB), then Wt bf16 [2048][512] (2 MB)
    bf16_t* xn = (bf16_t*)d_ws;
    bf16_t* Wt = (bf16_t*)((char*)d_ws + (size_t)M_ROWS * K_DIM * sizeof(bf16_t));

    add_ln_bf16<<<M_ROWS / 4, 256, 0, stream>>>(x203, x217, gamma, beta, xn);
    wt_bf16<<<(K_DIM / 32) * (N_DIM / 32), 256, 0, stream>>>(W, Wt);
    gemm_bias_gelu<<<(M_ROWS / BM) * (N_DIM / BN), 256, 0, stream>>>(xn, Wt, bias, out);
}

// Round 5
// 64.625 us; speedup vs baseline: 1.5351x; 1.5351x over previous
//
#include <hip/hip_runtime.h>
#include <hip/hip_bf16.h>

typedef __bf16 bf16_t;
typedef __bf16 bf16x8 __attribute__((ext_vector_type(8)));
typedef float  f32x4  __attribute__((ext_vector_type(4)));

#define M_ROWS 12544   // 64*14*14
#define K_DIM  512
#define N_DIM  2048
#define BM 128
#define BN 128
#define BK 64
#define TILES_M (M_ROWS / BM)      // 98
#define TILES_N (N_DIM / BN)       // 16
#define NBLK (TILES_M * TILES_N)   // 1568 (divisible by 8)

// ---------------- Kernel 1: residual add + LayerNorm -> bf16 ----------------
__global__ __launch_bounds__(256) void add_ln_bf16(
    const float* __restrict__ xa, const float* __restrict__ xb,
    const float* __restrict__ gamma, const float* __restrict__ beta,
    bf16_t* __restrict__ xn)
{
    const int wave = threadIdx.x >> 6;
    const int lane = threadIdx.x & 63;
    const int row  = blockIdx.x * 4 + wave;
    const size_t base = (size_t)row * K_DIM + lane * 8;

    float4 a0 = *(const float4*)(xa + base);
    float4 a1 = *(const float4*)(xa + base + 4);
    float4 b0 = *(const float4*)(xb + base);
    float4 b1 = *(const float4*)(xb + base + 4);

    float v[8] = {a0.x + b0.x, a0.y + b0.y, a0.z + b0.z, a0.w + b0.w,
                  a1.x + b1.x, a1.y + b1.y, a1.z + b1.z, a1.w + b1.w};
    float s = 0.f, sq = 0.f;
#pragma unroll
    for (int j = 0; j < 8; ++j) { s += v[j]; sq += v[j] * v[j]; }
#pragma unroll
    for (int off = 32; off >= 1; off >>= 1) {
        s  += __shfl_xor(s, off, 64);
        sq += __shfl_xor(sq, off, 64);
    }
    const float mean = s * (1.0f / 512.0f);
    const float var  = sq * (1.0f / 512.0f) - mean * mean;
    const float rstd = rsqrtf(var + 1e-5f);

    float4 g0  = *(const float4*)(gamma + lane * 8);
    float4 g1  = *(const float4*)(gamma + lane * 8 + 4);
    float4 be0 = *(const float4*)(beta  + lane * 8);
    float4 be1 = *(const float4*)(beta  + lane * 8 + 4);
    float g[8]  = {g0.x, g0.y, g0.z, g0.w, g1.x, g1.y, g1.z, g1.w};
    float bt[8] = {be0.x, be0.y, be0.z, be0.w, be1.x, be1.y, be1.z, be1.w};

    bf16x8 o;
#pragma unroll
    for (int j = 0; j < 8; ++j)
        o[j] = (bf16_t)((v[j] - mean) * rstd * g[j] + bt[j]);
    *(bf16x8*)(xn + base) = o;
}

// ---------------- Kernel 2: W [512][2048] f32 -> Wt [2048][512] bf16 --------
__global__ __launch_bounds__(256) void wt_bf16(
    const float* __restrict__ W, bf16_t* __restrict__ Wt)
{
    __shared__ float t[32][33];
    const int bk = blockIdx.x & 15;
    const int bn = blockIdx.x >> 4;
    const int tx = threadIdx.x & 31;
    const int ty = threadIdx.x >> 5;
#pragma unroll
    for (int r = 0; r < 4; ++r) {
        int k = bk * 32 + ty + r * 8;
        t[ty + r * 8][tx] = W[(size_t)k * N_DIM + bn * 32 + tx];
    }
    __syncthreads();
#pragma unroll
    for (int r = 0; r < 4; ++r) {
        int n = bn * 32 + ty + r * 8;
        Wt[(size_t)n * K_DIM + bk * 32 + tx] = (bf16_t)t[tx][ty + r * 8];
    }
}

// ---------------- Kernel 3: bf16 MFMA GEMM + bias + exact GELU --------------
__device__ __forceinline__ void gload_lds16(const bf16_t* g, bf16_t* l) {
    __builtin_amdgcn_global_load_lds(
        (const __attribute__((address_space(1))) void*)g,
        (__attribute__((address_space(3))) void*)l, 16, 0, 0);
}

// Branchless exact-GELU: erf via Abramowitz-Stegun 7.1.26 (|err| < ~2e-7)
__device__ __forceinline__ float gelu_f(float x) {
    const float y = fabsf(x) * 0.70710678118654752f;
    const float t = __builtin_amdgcn_rcpf(__builtin_fmaf(0.3275911f, y, 1.0f));
    float p = __builtin_fmaf(1.061405429f, t, -1.453152027f);
    p = __builtin_fmaf(p, t, 1.421413741f);
    p = __builtin_fmaf(p, t, -0.284496736f);
    p = __builtin_fmaf(p, t, 0.254829592f);
    p = p * t;
    const float e = __expf(-y * y);
    float er = __builtin_fmaf(-p, e, 1.0f);   // erf(|x|/sqrt2)
    er = __builtin_copysignf(er, x);
    return 0.5f * x * (1.0f + er);
}

__global__ __launch_bounds__(256) void gemm_bias_gelu(
    const bf16_t* __restrict__ A,   // [M_ROWS][K_DIM] bf16
    const bf16_t* __restrict__ Bt,  // [N_DIM][K_DIM]  bf16 (W^T)
    const float* __restrict__ bias, // [N_DIM]
    float* __restrict__ out)        // [M_ROWS][N_DIM] f32
{
    // Double-buffered, XOR-swizzled tiles. Linear LDS dest (global_load_lds
    // writes base + lane*16); swizzle realized by permuting the per-lane
    // GLOBAL source (rule #21: both-sides-or-neither).
    __shared__ bf16_t As[2][BM * BK];   // 2 x 16 KB
    __shared__ bf16_t Bs[2][BN * BK];   // 2 x 16 KB

    // XCD-chunked (bijective: 1568 % 8 == 0), tn-fast so 16 consecutive
    // blocks share one 128 KB A-panel and sweep all of B (2 MB) -> L2-fit.
    const int bid = blockIdx.x;
    const int wg  = (bid & 7) * (NBLK / 8) + (bid >> 3);
    const int tm  = wg >> 4;            // / TILES_N
    const int tn  = wg & 15;

    const int tid  = threadIdx.x;
    const int wave = tid >> 6;
    const int lane = tid & 63;
    const int wr = wave >> 1;
    const int wc = wave & 1;

    const bf16_t* Ab = A  + (size_t)tm * BM * K_DIM;
    const bf16_t* Bb = Bt + (size_t)tn * BN * K_DIM;

    // staging decomposition: seg = 8 rows x 64 k (512 elem = 1024 B = 64 lanes x 16 B)
    const int srow = lane >> 3;                 // row within segment
    const int jsrc = (lane & 7) ^ srow;         // inverse-swizzled 16B k-chunk

    f32x4 acc[4][4];
#pragma unroll
    for (int m = 0; m < 4; ++m)
#pragma unroll
        for (int n = 0; n < 4; ++n)
            acc[m][n] = (f32x4){0.f, 0.f, 0.f, 0.f};

    auto stage = [&](int buf, int k0) {
#pragma unroll
        for (int c = 0; c < 4; ++c) {
            const int seg = wave * 4 + c;       // wave-uniform LDS base
            const int row = seg * 8 + srow;
            gload_lds16(Ab + (size_t)row * K_DIM + k0 + jsrc * 8, &As[buf][seg * 512]);
            gload_lds16(Bb + (size_t)row * K_DIM + k0 + jsrc * 8, &Bs[buf][seg * 512]);
        }
    };

    stage(0, 0);   // prologue: 8 loads in flight

#pragma unroll
    for (int t = 0; t < K_DIM / BK; ++t) {
        const int cur = t & 1;
        if (t < K_DIM / BK - 1) {
            stage(cur ^ 1, (t + 1) * BK);                    // +8 loads (next tile)
            asm volatile("s_waitcnt vmcnt(8)" ::: "memory"); // tile t landed; next stays in flight
        } else {
            asm volatile("s_waitcnt vmcnt(0)" ::: "memory");
        }
        __builtin_amdgcn_s_barrier();

#pragma unroll
        for (int kk = 0; kk < 2; ++kk) {
            bf16x8 af[4], bfr[4];
            const int j = kk * 4 + (lane >> 4);  // 16B k-slot 0..7
#pragma unroll
            for (int m = 0; m < 4; ++m) {
                const int r = wr * 64 + m * 16 + (lane & 15);
                af[m] = *(const bf16x8*)(&As[cur][r * BK + ((j ^ (r & 7)) << 3)]);
            }
#pragma unroll
            for (int n = 0; n < 4; ++n) {
                const int r = wc * 64 + n * 16 + (lane & 15);
                bfr[n] = *(const bf16x8*)(&Bs[cur][r * BK + ((j ^ (r & 7)) << 3)]);
            }
#pragma unroll
            for (int m = 0; m < 4; ++m)
#pragma unroll
                for (int n = 0; n < 4; ++n)
                    acc[m][n] = __builtin_amdgcn_mfma_f32_16x16x32_bf16(
                        af[m], bfr[n], acc[m][n], 0, 0, 0);
        }
        if (t < K_DIM / BK - 1) __builtin_amdgcn_s_barrier();  // reads done before restage
    }

    // Epilogue: bias + exact GELU, nontemporal stores (write-once output,
    // keep L2 for A/B panels). C/D layout: col=lane&15, row=(lane>>4)*4+reg.
    const int rbase = tm * BM + wr * 64;
    const int cbase = tn * BN + wc * 64;
#pragma unroll
    for (int n = 0; n < 4; ++n) {
        const int col = cbase + n * 16 + (lane & 15);
        const float bv = bias[col];
#pragma unroll
        for (int m = 0; m < 4; ++m) {
            const int row0 = rbase + m * 16 + (lane >> 4) * 4;
#pragma unroll
            for (int i = 0; i < 4; ++i) {
                const float x = acc[m][n][i] + bv;
                __builtin_nontemporal_store(gelu_f(x),
                    out + (size_t)(row0 + i) * N_DIM + col);
            }
        }
    }
}

extern "C" void kernel_launch(void* const* d_in, const int* in_sizes, int n_in,
                              void* d_out, int out_size, void* d_ws, size_t ws_size,
                              hipStream_t stream)
{
    const float* x203  = (const float*)d_in[0];
    const float* x217  = (const float*)d_in[1];
    const float* gamma = (const float*)d_in[2];
    const float* beta  = (const float*)d_in[3];
    const float* W     = (const float*)d_in[4];
    const float* bias  = (const float*)d_in[5];
    float* out = (float*)d_out;

    bf16_t* xn = (bf16_t*)d_ws;
    bf16_t* Wt = (bf16_t*)((char*)d_ws + (size_t)M_ROWS * K_DIM * sizeof(bf16_t));

    add_ln_bf16<<<M_ROWS / 4, 256, 0, stream>>>(x203, x217, gamma, beta, xn);
    wt_bf16<<<(K_DIM / 32) * (N_DIM / 32), 256, 0, stream>>>(W, Wt);
    gemm_bias_gelu<<<NBLK, 256, 0, stream>>>(xn, Wt, bias, out);
}